// Round 1
// baseline (1589.322 us; speedup 1.0000x reference)
//
#include <hip/hip_runtime.h>

// ---------------- problem constants ----------------
#define HH 50
#define WW2 76
#define NPIX 3800
#define CIN 512
#define NANCH 34200     // 3800*9
#define NPRE 6000
#define NPOST 300
#define WPR 94          // ceil(6000/64) words per mask row

// ---------------- workspace byte offsets ----------------
// X:      512*3800*4          = 7,782,400
// BOXES:  34200*4*4           =   547,200
// KEYS:   34200*4             =   136,800
// HIST:   65536*4             =   262,144
// INFO:   16*4
// SELK:   8192*8              =    65,536
// BK:     6000*4*4            =    96,000
// MASK:   566016*8            = 4,528,128  (6016 rows x 94 words + slack)
#define OFF_X      0
#define OFF_BOXES  7782400
#define OFF_KEYS   8329600
#define OFF_HIST   8466400
#define OFF_INFO   8728544
#define OFF_SELK   8728608
#define OFF_BK     8794144
#define OFF_MASK   8890144
// total ~13.42 MB

typedef unsigned long long u64;
typedef unsigned int u32;

// ---------------- init: zero histogram + counters ----------------
__global__ void rpn_init(u32* __restrict__ hist, u32* __restrict__ info) {
    int idx = blockIdx.x * 256 + threadIdx.x;
    if (idx < 65536) hist[idx] = 0u;
    else if (idx < 65536 + 16) info[idx - 65536] = 0u;
}

// ---------------- conv1: 3x3, 512->512, pad 1, ReLU ----------------
// block: 256 thr = 64 outch (tx) x 4 pixel-quarters (ty); grid (50 rows, 8 ch-groups)
#define CB 16
__global__ __launch_bounds__(256) void rpn_conv1(
    const float* __restrict__ feat, const float* __restrict__ wgt,
    const float* __restrict__ bias, float* __restrict__ X) {
    const int y  = blockIdx.x;
    const int kg = blockIdx.y;
    const int tid = threadIdx.x;
    const int tx = tid & 63;
    const int ty = tid >> 6;
    __shared__ float in_l[CB * 3 * 80];
    __shared__ float w_l[144 * 65];
    float acc[19];
#pragma unroll
    for (int p = 0; p < 19; ++p) acc[p] = 0.f;
    const int x0 = ty * 19;
    for (int cc = 0; cc < CIN; cc += CB) {
        __syncthreads();
        // stage input: in_l[c][r][xx], xx=0..79 maps to gx=xx-1 (zero-padded)
        for (int idx = tid; idx < CB * 3 * 80; idx += 256) {
            int c = idx / 240, rem = idx % 240;
            int r = rem / 80, xx = rem % 80;
            int gx = xx - 1, gy = y - 1 + r;
            float v = 0.f;
            if (gx >= 0 && gx < WW2 && gy >= 0 && gy < HH)
                v = feat[(cc + c) * NPIX + gy * WW2 + gx];
            in_l[idx] = v;
        }
        // stage weights: w_l[(c*9+t)*65 + k]
        for (int idx = tid; idx < 64 * 144; idx += 256) {
            int k = idx / 144, ct = idx % 144;
            w_l[ct * 65 + k] = wgt[(kg * 64 + k) * 4608 + cc * 9 + ct];
        }
        __syncthreads();
#pragma unroll 1
        for (int c = 0; c < CB; ++c) {
#pragma unroll
            for (int r = 0; r < 3; ++r) {
                const float* wr = &w_l[(c * 9 + r * 3) * 65 + tx];
                float w0 = wr[0], w1 = wr[65], w2 = wr[130];
                const float* ir = &in_l[(c * 3 + r) * 80 + x0];
                float a0 = ir[0], a1 = ir[1];
#pragma unroll
                for (int p = 0; p < 19; ++p) {
                    float a2 = ir[p + 2];
                    acc[p] = fmaf(w0, a0, acc[p]);
                    acc[p] = fmaf(w1, a1, acc[p]);
                    acc[p] = fmaf(w2, a2, acc[p]);
                    a0 = a1; a1 = a2;
                }
            }
        }
    }
    const int k = kg * 64 + tx;
    const float b = bias[k];
    float* outp = &X[k * NPIX + y * WW2 + x0];
#pragma unroll
    for (int p = 0; p < 19; ++p) outp[p] = fmaxf(acc[p] + b, 0.f);
}

// ---------------- head: 1x1 convs + softmax + anchors + loc2bbox ----------------
// one wave per pixel
__global__ __launch_bounds__(64) void rpn_head(
    const float* __restrict__ X,
    const float* __restrict__ sw, const float* __restrict__ sb,
    const float* __restrict__ lw, const float* __restrict__ lb,
    const int* __restrict__ ihp, const int* __restrict__ iwp,
    float* __restrict__ out, float* __restrict__ boxes,
    u32* __restrict__ keys, u32* __restrict__ hist) {
    const int p = blockIdx.x;
    const int t = threadIdx.x;
    __shared__ __align__(16) float xs[CIN];
    __shared__ float ov[64];
    for (int c = t; c < CIN; c += 64) xs[c] = X[c * NPIX + p];
    __syncthreads();
    if (t < 54) {
        const float* wr = (t < 18) ? (sw + t * CIN) : (lw + (t - 18) * CIN);
        float a = 0.f;
#pragma unroll 4
        for (int c = 0; c < CIN; c += 4) {
            float4 wv = *reinterpret_cast<const float4*>(wr + c);
            float4 xv = *reinterpret_cast<const float4*>(xs + c);
            a = fmaf(wv.x, xv.x, a); a = fmaf(wv.y, xv.y, a);
            a = fmaf(wv.z, xv.z, a); a = fmaf(wv.w, xv.w, a);
        }
        a += (t < 18) ? sb[t] : lb[t - 18];
        ov[t] = a;
    }
    __syncthreads();
    if (t < 9) {
        const int a = t;
        const float s0 = ov[2 * a], s1 = ov[2 * a + 1];
        const float dy = ov[18 + 4 * a], dx = ov[18 + 4 * a + 1];
        const float dh = ov[18 + 4 * a + 2], dw = ov[18 + 4 * a + 3];
        const int yy = p / WW2, xx = p % WW2;
        const int ai = p * 9 + a;
        // rpn_locs
        *reinterpret_cast<float4*>(out + ai * 4) = make_float4(dy, dx, dh, dw);
        // rpn_scores
        *reinterpret_cast<float2*>(out + 136800 + ai * 2) = make_float2(s0, s1);
        // anchor base in f64, exactly like the numpy reference
        double r  = (a < 3) ? 0.5 : (a < 6) ? 1.0 : 2.0;
        int m3 = a % 3;
        double s2 = (m3 == 0) ? 8.0 : (m3 == 1) ? 16.0 : 32.0;
        double hd = (16.0 * s2) * sqrt(r);
        double wd = (16.0 * s2) * sqrt(1.0 / r);
        float ay1 = (float)(8.0 - hd * 0.5), ax1 = (float)(8.0 - wd * 0.5);
        float ay2 = (float)(8.0 + hd * 0.5), ax2 = (float)(8.0 + wd * 0.5);
        float fy = (float)(yy * 16), fx = (float)(xx * 16);
        float A0 = ay1 + fy, A1 = ax1 + fx, A2 = ay2 + fy, A3 = ax2 + fx;
        *reinterpret_cast<float4*>(out + 206400 + ai * 4) = make_float4(A0, A1, A2, A3);
        // loc2bbox (explicit non-contracted ops to mirror numpy rounding)
        float ah = __fsub_rn(A2, A0), aw = __fsub_rn(A3, A1);
        float cy = __fadd_rn(A0, __fmul_rn(0.5f, ah));
        float cx = __fadd_rn(A1, __fmul_rn(0.5f, aw));
        float ncy = __fadd_rn(__fmul_rn(dy, ah), cy);
        float ncx = __fadd_rn(__fmul_rn(dx, aw), cx);
        float nh = __fmul_rn(expf(dh), ah);
        float nw = __fmul_rn(expf(dw), aw);
        float b0 = __fsub_rn(ncy, __fmul_rn(0.5f, nh));
        float b1 = __fsub_rn(ncx, __fmul_rn(0.5f, nw));
        float b2 = __fadd_rn(ncy, __fmul_rn(0.5f, nh));
        float b3 = __fadd_rn(ncx, __fmul_rn(0.5f, nw));
        const float ch = (float)(*ihp), cw = (float)(*iwp);
        b0 = fminf(fmaxf(b0, 0.f), ch); b2 = fminf(fmaxf(b2, 0.f), ch);
        b1 = fminf(fmaxf(b1, 0.f), cw); b3 = fminf(fmaxf(b3, 0.f), cw);
        float hs = __fsub_rn(b2, b0), wsz = __fsub_rn(b3, b1);
        float m = fmaxf(s0, s1);
        float e0 = expf(__fsub_rn(s0, m)), e1 = expf(__fsub_rn(s1, m));
        float fg = __fdiv_rn(e1, __fadd_rn(e0, e1));
        float score = (hs >= 16.f && wsz >= 16.f) ? fg : -__builtin_inff();
        *reinterpret_cast<float4*>(boxes + ai * 4) = make_float4(b0, b1, b2, b3);
        u32 kb = __float_as_uint(score);
        kb = (kb & 0x80000000u) ? ~kb : (kb | 0x80000000u);
        keys[ai] = kb;
        atomicAdd(&hist[kb >> 16], 1u);
    }
}

// ---------------- find 6000-th threshold bin ----------------
__global__ __launch_bounds__(256) void rpn_thresh(const u32* __restrict__ hist,
                                                  u32* __restrict__ info) {
    __shared__ u32 part[256];
    const int t = threadIdx.x;
    u32 s = 0;
    for (int b = 0; b < 256; ++b) s += hist[t * 256 + b];
    part[t] = s;
    __syncthreads();
    if (t == 0) {
        u32 cum = 0; int seg = 255;
        for (; seg >= 0; --seg) {
            if (cum + part[seg] >= NPRE) break;
            cum += part[seg];
        }
        u32 T = 0, n = cum;
        if (seg >= 0) {
            int b = seg * 256 + 255;
            for (; b >= seg * 256; --b) { n += hist[b]; if (n >= NPRE) break; }
            T = (u32)b;
        }
        info[0] = T; info[1] = n;
    }
}

// ---------------- select candidates (bin >= T) ----------------
__global__ void rpn_select(const u32* __restrict__ keys, u32* __restrict__ info,
                           u64* __restrict__ selk) {
    int idx = blockIdx.x * 256 + threadIdx.x;
    if (idx >= NANCH) return;
    u32 k = keys[idx];
    if ((k >> 16) >= info[0]) {
        u32 pos = atomicAdd(&info[2], 1u);
        if (pos < 8192) selk[pos] = ((u64)k << 32) | (u64)(0xFFFFFFFFu - (u32)idx);
    }
}

// ---------------- bitonic sort 8192 u64 desc; gather top-6000 boxes ----------------
__global__ __launch_bounds__(512) void rpn_sort(const u64* __restrict__ selk,
                                                const u32* __restrict__ info,
                                                const float* __restrict__ boxes,
                                                float* __restrict__ bk) {
    __shared__ u64 s[8192];
    const int t = threadIdx.x;
    int n = (int)info[2]; if (n > 8192) n = 8192;
    for (int i = t; i < 8192; i += 512) s[i] = (i < n) ? selk[i] : 0ull;
    __syncthreads();
    for (int k = 2; k <= 8192; k <<= 1) {
        for (int j = k >> 1; j > 0; j >>= 1) {
            for (int i = t; i < 8192; i += 512) {
                int ixj = i ^ j;
                if (ixj > i) {
                    u64 A = s[i], B = s[ixj];
                    bool desc = ((i & k) == 0);
                    if (desc ? (A < B) : (A > B)) { s[i] = B; s[ixj] = A; }
                }
            }
            __syncthreads();
        }
    }
    for (int r = t; r < NPRE; r += 512) {
        u32 oi = 0xFFFFFFFFu - (u32)(s[r] & 0xFFFFFFFFull);
        if (oi >= NANCH) oi = 0;
        reinterpret_cast<float4*>(bk)[r] = reinterpret_cast<const float4*>(boxes)[oi];
    }
}

// ---------------- IoU bitmask: bit jj of mask[i][bx] <=> iou(i, bx*64+jj)>0.7 & j>i ----
__global__ __launch_bounds__(64) void rpn_iou(const float* __restrict__ bk,
                                              u64* __restrict__ mask) {
    const int t = threadIdx.x;
    const int bj = blockIdx.x, bi = blockIdx.y;
    __shared__ float4 jb[64];
    const int j0 = bj * 64;
    jb[t] = (j0 + t < NPRE) ? reinterpret_cast<const float4*>(bk)[j0 + t]
                            : make_float4(0.f, 0.f, 0.f, 0.f);
    __syncthreads();
    const int i = bi * 64 + t;
    if (i >= NPRE) return;
    float4 b = reinterpret_cast<const float4*>(bk)[i];
    float areai = __fmul_rn(__fsub_rn(b.z, b.x), __fsub_rn(b.w, b.y));
    u64 bits = 0ull;
    for (int jj = 0; jj < 64; ++jj) {
        int j = j0 + jj;
        if (j <= i || j >= NPRE) continue;
        float4 c = jb[jj];
        float ty = fmaxf(b.x, c.x), tx = fmaxf(b.y, c.y);
        float by = fminf(b.z, c.z), bx2 = fminf(b.w, c.w);
        float ih = fmaxf(__fsub_rn(by, ty), 0.f);
        float iw = fmaxf(__fsub_rn(bx2, tx), 0.f);
        float inter = __fmul_rn(ih, iw);
        float areaj = __fmul_rn(__fsub_rn(c.z, c.x), __fsub_rn(c.w, c.y));
        float denom = __fadd_rn(__fsub_rn(__fadd_rn(areai, areaj), inter), 1e-9f);
        float iou = __fdiv_rn(inter, denom);
        if (iou > 0.7f) bits |= (1ull << jj);
    }
    mask[(size_t)i * WPR + bj] = bits;
}

// ---------------- sequential greedy NMS (single wave) + emit 300 rois ----------------
__global__ __launch_bounds__(64) void rpn_nms(const u64* __restrict__ mask,
                                              const float* __restrict__ bk,
                                              float* __restrict__ rois) {
    const int lane = threadIdx.x;
    u64 rem0 = 0ull, rem1 = 0ull, curW = 0ull;
    __shared__ unsigned short klist[304];
    int kcnt = 0;
    u64 pm0[16], pm1[16], pmg[16];
#pragma unroll
    for (int u = 0; u < 16; ++u) {
        pm0[u] = mask[(size_t)u * WPR + lane];
        pm1[u] = mask[(size_t)u * WPR + 64 + lane];   // lanes>=30 read slack, unused
        pmg[u] = mask[(size_t)u * WPR + 0];
    }
    for (int base = 0; base < NPRE; base += 16) {
        if ((base & 63) == 0) {
            int w = base >> 6;
            curW = (w < 64) ? __shfl(rem0, w) : __shfl(rem1, w - 64);
        }
#pragma unroll
        for (int u = 0; u < 16; ++u) {
            const int i = base + u;
            u64 m0 = pm0[u], m1 = pm1[u], mg = pmg[u];
            const int ni = i + 16;   // always < 6016; mask buffer has slack rows
            pm0[u] = mask[(size_t)ni * WPR + lane];
            pm1[u] = mask[(size_t)ni * WPR + 64 + lane];
            pmg[u] = mask[(size_t)ni * WPR + (ni >> 6)];
            if (((curW >> (i & 63)) & 1ull) == 0ull) {   // box i kept (uniform)
                rem0 |= m0;
                if (lane < 30) rem1 |= m1;
                curW |= mg;
                if (lane == 0 && kcnt < 304) klist[kcnt] = (unsigned short)i;
                ++kcnt;
            }
        }
    }
    __syncthreads();
    const int nk = kcnt < NPOST ? kcnt : NPOST;
    for (int r = lane; r < nk; r += 64) {
        int bi = klist[r];
        reinterpret_cast<float4*>(rois)[r] = reinterpret_cast<const float4*>(bk)[bi];
    }
    if (kcnt < NPOST) {   // pad with suppressed boxes in ascending index order
        int pos = kcnt;
        for (int i = 0; i < NPRE && pos < NPOST; ++i) {
            int w = i >> 6;
            u64 wv = (w < 64) ? __shfl(rem0, w) : __shfl(rem1, w - 64);
            if ((wv >> (i & 63)) & 1ull) {
                if (lane < 4) rois[pos * 4 + lane] = bk[i * 4 + lane];
                ++pos;
            }
        }
    }
}

extern "C" void kernel_launch(void* const* d_in, const int* in_sizes, int n_in,
                              void* d_out, int out_size, void* d_ws, size_t ws_size,
                              hipStream_t stream) {
    (void)in_sizes; (void)n_in; (void)out_size; (void)ws_size;
    const float* feat = (const float*)d_in[0];
    const float* w1   = (const float*)d_in[1];
    const float* b1   = (const float*)d_in[2];
    const float* sw   = (const float*)d_in[3];
    const float* sb   = (const float*)d_in[4];
    const float* lw   = (const float*)d_in[5];
    const float* lb   = (const float*)d_in[6];
    const int*   ih   = (const int*)d_in[7];
    const int*   iw   = (const int*)d_in[8];
    float* out = (float*)d_out;
    char*  ws  = (char*)d_ws;
    float* X      = (float*)(ws + OFF_X);
    float* boxes  = (float*)(ws + OFF_BOXES);
    u32*   keys   = (u32*)(ws + OFF_KEYS);
    u32*   hist   = (u32*)(ws + OFF_HIST);
    u32*   info   = (u32*)(ws + OFF_INFO);
    u64*   selk   = (u64*)(ws + OFF_SELK);
    float* bk     = (float*)(ws + OFF_BK);
    u64*   mask   = (u64*)(ws + OFF_MASK);

    rpn_init<<<258, 256, 0, stream>>>(hist, info);
    rpn_conv1<<<dim3(HH, 8), 256, 0, stream>>>(feat, w1, b1, X);
    rpn_head<<<NPIX, 64, 0, stream>>>(X, sw, sb, lw, lb, ih, iw, out, boxes, keys, hist);
    rpn_thresh<<<1, 256, 0, stream>>>(hist, info);
    rpn_select<<<(NANCH + 255) / 256, 256, 0, stream>>>(keys, info, selk);
    rpn_sort<<<1, 512, 0, stream>>>(selk, info, boxes, bk);
    rpn_iou<<<dim3(WPR, WPR), 64, 0, stream>>>(bk, mask);
    rpn_nms<<<1, 64, 0, stream>>>(mask, bk, out + 205200);
}

// Round 2
// 1006.323 us; speedup vs baseline: 1.5793x; 1.5793x over previous
//
#include <hip/hip_runtime.h>

// ---------------- problem constants ----------------
#define HH 50
#define WW2 76
#define NPIX 3800
#define CIN 512
#define NANCH 34200     // 3800*9
#define NPRE 6000
#define NPOST 300
#define WPR 94          // ceil(6000/64) words per mask row

// ---------------- workspace byte offsets ----------------
// XP:     2*512*3800*4        = 15,564,800   (split-K partials)
// XT:     3800*512*4          =  7,782,400   (pixel-major, post bias+relu)
// BOXES:  34200*4*4           =    547,200
// KEYS:   34200*4             =    136,800
// HIST:   65536*4             =    262,144
// INFO:   16*4
// SELK:   8192*8              =     65,536
// BK:     6000*4*4            =     96,000
// MASK:   566016*8            =  4,528,128
#define OFF_XP     0
#define OFF_XT     15564800
#define OFF_BOXES  23347200
#define OFF_KEYS   23894400
#define OFF_HIST   24031200
#define OFF_INFO   24293344
#define OFF_SELK   24293408
#define OFF_BK     24358944
#define OFF_MASK   24454944
// total ~29.0 MB

typedef unsigned long long u64;
typedef unsigned int u32;

// ---------------- init: zero histogram + counters ----------------
__global__ void rpn_init(u32* __restrict__ hist, u32* __restrict__ info) {
    int idx = blockIdx.x * 256 + threadIdx.x;
    if (idx < 65536) hist[idx] = 0u;
    else if (idx < 65536 + 16) info[idx - 65536] = 0u;
}

// ---------------- conv1: 3x3, 512->512, pad 1, split-K partials ----------------
// block: 256 thr = 32 outch-pairs (kp) x 8 pixel-groups (ty, 10 px each)
// grid: (50 rows, 8 kgroups of 64 outch, 2 K-splits of 256 inch)
#define CB8 8
__global__ __launch_bounds__(256, 4) void rpn_conv1(
    const float* __restrict__ feat, const float* __restrict__ wgt,
    float* __restrict__ Xp) {
    const int y  = blockIdx.x;
    const int kg = blockIdx.y;
    const int cz = blockIdx.z;
    const int t  = threadIdx.x;
    const int kp = t & 31;
    const int ty = t >> 5;
    __shared__ float in_l[CB8 * 3 * 84];      // [c][r][84], gx = xx-1
    __shared__ float w_l[CB8 * 18 * 33];      // [(c*18+j)*33 + kp], j = kd*9+tap
    float acc0[10], acc1[10];
#pragma unroll
    for (int p = 0; p < 10; ++p) { acc0[p] = 0.f; acc1[p] = 0.f; }
    const int x0 = ty * 10;
    const int cbase = cz * 256;
    const float* wbase = wgt + (size_t)(kg * 64) * 4608 + (size_t)cbase * 9;
    for (int cc = 0; cc < 256; cc += CB8) {
        __syncthreads();
        // stage input: 8c x 3r x 84 = 2016 floats
        for (int idx = t; idx < CB8 * 3 * 84; idx += 256) {
            int c = idx / 252, rem = idx - c * 252;
            int r = rem / 84,  xx = rem - r * 84;
            int gy = y - 1 + r, gx = xx - 1;
            float v = 0.f;
            if ((unsigned)gx < 76u && (unsigned)gy < 50u)
                v = feat[(size_t)(cbase + cc + c) * NPIX + gy * 76 + gx];
            in_l[idx] = v;
        }
        // stage weights: 64k x 8c x 9tap = 4608 floats (coalesced src runs of 72)
        for (int it = 0; it < 18; ++it) {
            int idx = t + it * 256;
            int k = idx / 72, m = idx - k * 72;
            int c = m / 9,  tap = m - c * 9;
            float v = wbase[(size_t)k * 4608 + (cc + c) * 9 + tap];
            w_l[(c * 18 + (k & 1) * 9 + tap) * 33 + (k >> 1)] = v;
        }
        __syncthreads();
#pragma unroll 1
        for (int c = 0; c < CB8; ++c) {
            const float* wl = &w_l[c * 18 * 33 + kp];
#pragma unroll
            for (int r = 0; r < 3; ++r) {
                const float* ir = &in_l[(c * 3 + r) * 84 + x0];
                float2 i0 = *reinterpret_cast<const float2*>(ir + 0);
                float2 i1 = *reinterpret_cast<const float2*>(ir + 2);
                float2 i2 = *reinterpret_cast<const float2*>(ir + 4);
                float2 i3 = *reinterpret_cast<const float2*>(ir + 6);
                float2 i4 = *reinterpret_cast<const float2*>(ir + 8);
                float2 i5 = *reinterpret_cast<const float2*>(ir + 10);
                float win[12] = { i0.x, i0.y, i1.x, i1.y, i2.x, i2.y,
                                  i3.x, i3.y, i4.x, i4.y, i5.x, i5.y };
                float w00 = wl[(r * 3 + 0) * 33];
                float w01 = wl[(r * 3 + 1) * 33];
                float w02 = wl[(r * 3 + 2) * 33];
                float w10 = wl[(9 + r * 3 + 0) * 33];
                float w11 = wl[(9 + r * 3 + 1) * 33];
                float w12 = wl[(9 + r * 3 + 2) * 33];
#pragma unroll
                for (int p = 0; p < 10; ++p) {
                    acc0[p] = fmaf(w00, win[p],     acc0[p]);
                    acc0[p] = fmaf(w01, win[p + 1], acc0[p]);
                    acc0[p] = fmaf(w02, win[p + 2], acc0[p]);
                    acc1[p] = fmaf(w10, win[p],     acc1[p]);
                    acc1[p] = fmaf(w11, win[p + 1], acc1[p]);
                    acc1[p] = fmaf(w12, win[p + 2], acc1[p]);
                }
            }
        }
    }
    const int k0 = kg * 64 + kp * 2;
    float* d0 = &Xp[((size_t)cz * 512 + k0) * NPIX + y * 76 + x0];
#pragma unroll
    for (int p = 0; p < 10; p += 2) {
        if (x0 + p + 1 < 76) {
            *reinterpret_cast<float2*>(d0 + p)        = make_float2(acc0[p], acc0[p + 1]);
            *reinterpret_cast<float2*>(d0 + NPIX + p) = make_float2(acc1[p], acc1[p + 1]);
        }
    }
}

// ---------------- combine: reduce split-K + bias + relu + transpose ----------------
// X_t[p][c] = relu(Xp[0][c][p] + Xp[1][c][p] + b[c]); grid (15, 32), 256 thr
__global__ __launch_bounds__(256) void rpn_combine(
    const float* __restrict__ Xp, const float* __restrict__ bias,
    float* __restrict__ Xt) {
    const int p0 = blockIdx.x * 256;
    const int c0 = blockIdx.y * 16;
    const int t  = threadIdx.x;
    __shared__ float s[16][257];
    const int p = p0 + t;
#pragma unroll 4
    for (int i = 0; i < 16; ++i) {
        float v = 0.f;
        if (p < NPIX) {
            size_t base = (size_t)(c0 + i) * NPIX + p;
            v = fmaxf(Xp[base] + Xp[(size_t)512 * NPIX + base] + bias[c0 + i], 0.f);
        }
        s[i][t] = v;
    }
    __syncthreads();
    const int cs = (t & 3) * 4;
    const int pr = t >> 2;
#pragma unroll
    for (int q = 0; q < 4; ++q) {
        int p2 = p0 + pr + q * 64;
        if (p2 < NPIX) {
            int pi = pr + q * 64;
            float4 v = make_float4(s[cs][pi], s[cs + 1][pi], s[cs + 2][pi], s[cs + 3][pi]);
            *reinterpret_cast<float4*>(&Xt[(size_t)p2 * 512 + c0 + cs]) = v;
        }
    }
}

// ---------------- head: 1x1 convs + softmax + anchors + loc2bbox ----------------
__global__ __launch_bounds__(64) void rpn_head(
    const float* __restrict__ Xt,
    const float* __restrict__ sw, const float* __restrict__ sb,
    const float* __restrict__ lw, const float* __restrict__ lb,
    const int* __restrict__ ihp, const int* __restrict__ iwp,
    float* __restrict__ out, float* __restrict__ boxes,
    u32* __restrict__ keys, u32* __restrict__ hist) {
    const int p = blockIdx.x;
    const int t = threadIdx.x;
    __shared__ __align__(16) float xs[CIN];
    __shared__ float ov[64];
    const float4* xr = reinterpret_cast<const float4*>(Xt + (size_t)p * 512);
    reinterpret_cast<float4*>(xs)[t]      = xr[t];
    reinterpret_cast<float4*>(xs)[t + 64] = xr[t + 64];
    __syncthreads();
    if (t < 54) {
        const float* wr = (t < 18) ? (sw + t * CIN) : (lw + (t - 18) * CIN);
        float a = 0.f;
#pragma unroll 4
        for (int c = 0; c < CIN; c += 4) {
            float4 wv = *reinterpret_cast<const float4*>(wr + c);
            float4 xv = *reinterpret_cast<const float4*>(xs + c);
            a = fmaf(wv.x, xv.x, a); a = fmaf(wv.y, xv.y, a);
            a = fmaf(wv.z, xv.z, a); a = fmaf(wv.w, xv.w, a);
        }
        a += (t < 18) ? sb[t] : lb[t - 18];
        ov[t] = a;
    }
    __syncthreads();
    if (t < 9) {
        const int a = t;
        const float s0 = ov[2 * a], s1 = ov[2 * a + 1];
        const float dy = ov[18 + 4 * a], dx = ov[18 + 4 * a + 1];
        const float dh = ov[18 + 4 * a + 2], dw = ov[18 + 4 * a + 3];
        const int yy = p / WW2, xx = p % WW2;
        const int ai = p * 9 + a;
        *reinterpret_cast<float4*>(out + ai * 4) = make_float4(dy, dx, dh, dw);
        *reinterpret_cast<float2*>(out + 136800 + ai * 2) = make_float2(s0, s1);
        double r  = (a < 3) ? 0.5 : (a < 6) ? 1.0 : 2.0;
        int m3 = a % 3;
        double s2 = (m3 == 0) ? 8.0 : (m3 == 1) ? 16.0 : 32.0;
        double hd = (16.0 * s2) * sqrt(r);
        double wd = (16.0 * s2) * sqrt(1.0 / r);
        float ay1 = (float)(8.0 - hd * 0.5), ax1 = (float)(8.0 - wd * 0.5);
        float ay2 = (float)(8.0 + hd * 0.5), ax2 = (float)(8.0 + wd * 0.5);
        float fy = (float)(yy * 16), fx = (float)(xx * 16);
        float A0 = ay1 + fy, A1 = ax1 + fx, A2 = ay2 + fy, A3 = ax2 + fx;
        *reinterpret_cast<float4*>(out + 206400 + ai * 4) = make_float4(A0, A1, A2, A3);
        float ah = __fsub_rn(A2, A0), aw = __fsub_rn(A3, A1);
        float cy = __fadd_rn(A0, __fmul_rn(0.5f, ah));
        float cx = __fadd_rn(A1, __fmul_rn(0.5f, aw));
        float ncy = __fadd_rn(__fmul_rn(dy, ah), cy);
        float ncx = __fadd_rn(__fmul_rn(dx, aw), cx);
        float nh = __fmul_rn(expf(dh), ah);
        float nw = __fmul_rn(expf(dw), aw);
        float b0 = __fsub_rn(ncy, __fmul_rn(0.5f, nh));
        float b1 = __fsub_rn(ncx, __fmul_rn(0.5f, nw));
        float b2 = __fadd_rn(ncy, __fmul_rn(0.5f, nh));
        float b3 = __fadd_rn(ncx, __fmul_rn(0.5f, nw));
        const float ch = (float)(*ihp), cw = (float)(*iwp);
        b0 = fminf(fmaxf(b0, 0.f), ch); b2 = fminf(fmaxf(b2, 0.f), ch);
        b1 = fminf(fmaxf(b1, 0.f), cw); b3 = fminf(fmaxf(b3, 0.f), cw);
        float hs = __fsub_rn(b2, b0), wsz = __fsub_rn(b3, b1);
        float m = fmaxf(s0, s1);
        float e0 = expf(__fsub_rn(s0, m)), e1 = expf(__fsub_rn(s1, m));
        float fg = __fdiv_rn(e1, __fadd_rn(e0, e1));
        float score = (hs >= 16.f && wsz >= 16.f) ? fg : -__builtin_inff();
        *reinterpret_cast<float4*>(boxes + ai * 4) = make_float4(b0, b1, b2, b3);
        u32 kb = __float_as_uint(score);
        kb = (kb & 0x80000000u) ? ~kb : (kb | 0x80000000u);
        keys[ai] = kb;
        atomicAdd(&hist[kb >> 16], 1u);
    }
}

// ---------------- find 6000-th threshold bin ----------------
__global__ __launch_bounds__(256) void rpn_thresh(const u32* __restrict__ hist,
                                                  u32* __restrict__ info) {
    __shared__ u32 part[256];
    const int t = threadIdx.x;
    u32 s = 0;
    for (int b = 0; b < 256; ++b) s += hist[t * 256 + b];
    part[t] = s;
    __syncthreads();
    if (t == 0) {
        u32 cum = 0; int seg = 255;
        for (; seg >= 0; --seg) {
            if (cum + part[seg] >= NPRE) break;
            cum += part[seg];
        }
        u32 T = 0, n = cum;
        if (seg >= 0) {
            int b = seg * 256 + 255;
            for (; b >= seg * 256; --b) { n += hist[b]; if (n >= NPRE) break; }
            T = (u32)b;
        }
        info[0] = T; info[1] = n;
    }
}

// ---------------- select candidates (bin >= T) ----------------
__global__ void rpn_select(const u32* __restrict__ keys, u32* __restrict__ info,
                           u64* __restrict__ selk) {
    int idx = blockIdx.x * 256 + threadIdx.x;
    if (idx >= NANCH) return;
    u32 k = keys[idx];
    if ((k >> 16) >= info[0]) {
        u32 pos = atomicAdd(&info[2], 1u);
        if (pos < 8192) selk[pos] = ((u64)k << 32) | (u64)(0xFFFFFFFFu - (u32)idx);
    }
}

// ---------------- bitonic sort 8192 u64 desc; gather top-6000 boxes ----------------
__global__ __launch_bounds__(512) void rpn_sort(const u64* __restrict__ selk,
                                                const u32* __restrict__ info,
                                                const float* __restrict__ boxes,
                                                float* __restrict__ bk) {
    __shared__ u64 s[8192];
    const int t = threadIdx.x;
    int n = (int)info[2]; if (n > 8192) n = 8192;
    for (int i = t; i < 8192; i += 512) s[i] = (i < n) ? selk[i] : 0ull;
    __syncthreads();
    for (int k = 2; k <= 8192; k <<= 1) {
        for (int j = k >> 1; j > 0; j >>= 1) {
            for (int i = t; i < 8192; i += 512) {
                int ixj = i ^ j;
                if (ixj > i) {
                    u64 A = s[i], B = s[ixj];
                    bool desc = ((i & k) == 0);
                    if (desc ? (A < B) : (A > B)) { s[i] = B; s[ixj] = A; }
                }
            }
            __syncthreads();
        }
    }
    for (int r = t; r < NPRE; r += 512) {
        u32 oi = 0xFFFFFFFFu - (u32)(s[r] & 0xFFFFFFFFull);
        if (oi >= NANCH) oi = 0;
        reinterpret_cast<float4*>(bk)[r] = reinterpret_cast<const float4*>(boxes)[oi];
    }
}

// ---------------- IoU bitmask ----------------
__global__ __launch_bounds__(64) void rpn_iou(const float* __restrict__ bk,
                                              u64* __restrict__ mask) {
    const int t = threadIdx.x;
    const int bj = blockIdx.x, bi = blockIdx.y;
    __shared__ float4 jb[64];
    const int j0 = bj * 64;
    jb[t] = (j0 + t < NPRE) ? reinterpret_cast<const float4*>(bk)[j0 + t]
                            : make_float4(0.f, 0.f, 0.f, 0.f);
    __syncthreads();
    const int i = bi * 64 + t;
    if (i >= NPRE) return;
    float4 b = reinterpret_cast<const float4*>(bk)[i];
    float areai = __fmul_rn(__fsub_rn(b.z, b.x), __fsub_rn(b.w, b.y));
    u64 bits = 0ull;
    for (int jj = 0; jj < 64; ++jj) {
        int j = j0 + jj;
        if (j <= i || j >= NPRE) continue;
        float4 c = jb[jj];
        float ty = fmaxf(b.x, c.x), tx = fmaxf(b.y, c.y);
        float by = fminf(b.z, c.z), bx2 = fminf(b.w, c.w);
        float ih = fmaxf(__fsub_rn(by, ty), 0.f);
        float iw = fmaxf(__fsub_rn(bx2, tx), 0.f);
        float inter = __fmul_rn(ih, iw);
        float areaj = __fmul_rn(__fsub_rn(c.z, c.x), __fsub_rn(c.w, c.y));
        float denom = __fadd_rn(__fsub_rn(__fadd_rn(areai, areaj), inter), 1e-9f);
        float iou = __fdiv_rn(inter, denom);
        if (iou > 0.7f) bits |= (1ull << jj);
    }
    mask[(size_t)i * WPR + bj] = bits;
}

// ---------------- sequential greedy NMS (single wave, early-exit) ----------------
__global__ __launch_bounds__(64) void rpn_nms(const u64* __restrict__ mask,
                                              const float* __restrict__ bk,
                                              float* __restrict__ rois) {
    const int lane = threadIdx.x;
    u64 rem0 = 0ull, rem1 = 0ull, curW = 0ull;
    __shared__ unsigned short klist[304];
    int kcnt = 0;
    u64 pm0[16], pm1[16], pmg[16];
#pragma unroll
    for (int u = 0; u < 16; ++u) {
        pm0[u] = mask[(size_t)u * WPR + lane];
        pm1[u] = mask[(size_t)u * WPR + 64 + lane];
        pmg[u] = mask[(size_t)u * WPR + 0];
    }
    bool done = false;
    for (int base = 0; base < NPRE && !done; base += 16) {
        if ((base & 63) == 0) {
            int w = base >> 6;
            curW = (w < 64) ? __shfl(rem0, w) : __shfl(rem1, w - 64);
        }
#pragma unroll
        for (int u = 0; u < 16; ++u) {
            const int i = base + u;
            u64 m0 = pm0[u], m1 = pm1[u], mg = pmg[u];
            const int ni = i + 16;
            pm0[u] = mask[(size_t)ni * WPR + lane];
            pm1[u] = mask[(size_t)ni * WPR + 64 + lane];
            pmg[u] = mask[(size_t)ni * WPR + (ni >> 6)];
            if (((curW >> (i & 63)) & 1ull) == 0ull) {
                rem0 |= m0;
                if (lane < 30) rem1 |= m1;
                curW |= mg;
                if (lane == 0 && kcnt < 304) klist[kcnt] = (unsigned short)i;
                ++kcnt;
                if (kcnt >= NPOST) { done = true; break; }
            }
        }
    }
    __syncthreads();
    const int nk = kcnt < NPOST ? kcnt : NPOST;
    for (int r = lane; r < nk; r += 64) {
        int bi = klist[r];
        reinterpret_cast<float4*>(rois)[r] = reinterpret_cast<const float4*>(bk)[bi];
    }
    if (kcnt < NPOST) {
        int pos = kcnt;
        for (int i = 0; i < NPRE && pos < NPOST; ++i) {
            int w = i >> 6;
            u64 wv = (w < 64) ? __shfl(rem0, w) : __shfl(rem1, w - 64);
            if ((wv >> (i & 63)) & 1ull) {
                if (lane < 4) rois[pos * 4 + lane] = bk[i * 4 + lane];
                ++pos;
            }
        }
    }
}

extern "C" void kernel_launch(void* const* d_in, const int* in_sizes, int n_in,
                              void* d_out, int out_size, void* d_ws, size_t ws_size,
                              hipStream_t stream) {
    (void)in_sizes; (void)n_in; (void)out_size; (void)ws_size;
    const float* feat = (const float*)d_in[0];
    const float* w1   = (const float*)d_in[1];
    const float* b1   = (const float*)d_in[2];
    const float* sw   = (const float*)d_in[3];
    const float* sb   = (const float*)d_in[4];
    const float* lw   = (const float*)d_in[5];
    const float* lb   = (const float*)d_in[6];
    const int*   ih   = (const int*)d_in[7];
    const int*   iw   = (const int*)d_in[8];
    float* out = (float*)d_out;
    char*  ws  = (char*)d_ws;
    float* Xp     = (float*)(ws + OFF_XP);
    float* Xt     = (float*)(ws + OFF_XT);
    float* boxes  = (float*)(ws + OFF_BOXES);
    u32*   keys   = (u32*)(ws + OFF_KEYS);
    u32*   hist   = (u32*)(ws + OFF_HIST);
    u32*   info   = (u32*)(ws + OFF_INFO);
    u64*   selk   = (u64*)(ws + OFF_SELK);
    float* bk     = (float*)(ws + OFF_BK);
    u64*   mask   = (u64*)(ws + OFF_MASK);

    rpn_init<<<258, 256, 0, stream>>>(hist, info);
    rpn_conv1<<<dim3(HH, 8, 2), 256, 0, stream>>>(feat, w1, Xp);
    rpn_combine<<<dim3(15, 32), 256, 0, stream>>>(Xp, b1, Xt);
    rpn_head<<<NPIX, 64, 0, stream>>>(Xt, sw, sb, lw, lb, ih, iw, out, boxes, keys, hist);
    rpn_thresh<<<1, 256, 0, stream>>>(hist, info);
    rpn_select<<<(NANCH + 255) / 256, 256, 0, stream>>>(keys, info, selk);
    rpn_sort<<<1, 512, 0, stream>>>(selk, info, boxes, bk);
    rpn_iou<<<dim3(WPR, WPR), 64, 0, stream>>>(bk, mask);
    rpn_nms<<<1, 64, 0, stream>>>(mask, bk, out + 205200);
}

// Round 3
// 841.114 us; speedup vs baseline: 1.8895x; 1.1964x over previous
//
#include <hip/hip_runtime.h>

// ---------------- problem constants ----------------
#define HH 50
#define WW2 76
#define NPIX 3800
#define CIN 512
#define NANCH 34200     // 3800*9
#define NPRE 6000
#define NPOST 300
#define WPR 94          // ceil(6000/64) words per mask row

typedef unsigned long long u64;
typedef unsigned int u32;

// ---------------- init: zero histogram + counters ----------------
__global__ void rpn_init(u32* __restrict__ hist, u32* __restrict__ info) {
    int idx = blockIdx.x * 256 + threadIdx.x;
    if (idx < 65536) hist[idx] = 0u;
    else if (idx < 65536 + 16) info[idx - 65536] = 0u;
}

// ---------------- weight transpose: wt[(ci*9+tap)*512 + ko] ----------------
__global__ __launch_bounds__(256) void rpn_wtrans(const float* __restrict__ wgt,
                                                  float* __restrict__ wt) {
    int id = blockIdx.x * 256 + threadIdx.x;   // < 512*512*9 = 2359296
    int ko = id & 511;
    int tmp = id >> 9;            // ci*9 + tap
    int tap = tmp % 9, ci = tmp / 9;
    wt[id] = wgt[(size_t)ko * 4608 + ci * 9 + tap];
}

// ---------------- conv1: 3x3, 512->512, pad 1, split-K partials ----------------
// grid (25 y-pairs, 8 kgroups, nz); block 256 = 32 kp x 8 ty (row,xseg)
// per thread: 2 outch x 20 px of one row. CB=8 input channels per LDS tile.
// LDS weight layout: w_l[c*576 + tapIdx*64 + ko]  (c<8, tapIdx<9, ko<64)
// LDS input  layout: in_l[(c*4 + r)*84 + xx], gx = xx-1 (zero-padded)
template <bool USEWT>
__global__ __launch_bounds__(256, 4) void rpn_conv1(
    const float* __restrict__ feat, const float* __restrict__ wsrc,
    float* __restrict__ Xp, int cin_blk) {
    const int yb = blockIdx.x;
    const int kg = blockIdx.y;
    const int cz = blockIdx.z;
    const int t  = threadIdx.x;
    const int kp = t & 31;
    const int ty = t >> 5;
    const int row  = ty >> 2;
    const int xseg = ty & 3;
    const int x0 = xseg * 20;
    __shared__ float in_l[2816];       // 8c*4r*84 = 2688 used
    __shared__ float w_l[4608];        // 18 chunks of 256, exact

    // ---- input staging: slot q = t + k*256 (k<11), decode ONCE ----
    const int y0 = yb * 2 - 1;
    int inSrc[11]; u32 inValid = 0, inPad = 0;
#pragma unroll
    for (int k = 0; k < 11; ++k) {
        int q = t + k * 256;
        int c = q / 336, rem = q - c * 336;
        int r = rem / 84, xx = rem - r * 84;
        int gy = y0 + r, gx = xx - 1;
        bool inb = q < 2688;
        bool ok = inb && ((unsigned)gy < 50u) && ((unsigned)gx < 76u);
        inSrc[k] = c * NPIX + gy * 76 + gx;
        if (ok) inValid |= (1u << k);
        else if (inb) inPad |= (1u << k);
    }
#pragma unroll
    for (int k = 0; k < 11; ++k)
        if ((inPad >> k) & 1) in_l[t + k * 256] = 0.f;   // zero-pad once

    // ---- weight staging setup ----
    const float* wb;
    int wOffA = 0;        // USEWT affine base
    int wSrc[18];         // non-WT per-chunk sources
    if (USEWT) {
        wb = wsrc + (size_t)(cz * cin_blk) * 9 * 512 + kg * 64;
        wOffA = 8 * t - 7 * (t & 63);
    } else {
        wb = wsrc + (size_t)(kg * 64) * 4608 + (size_t)(cz * cin_blk) * 9;
#pragma unroll
        for (int k = 0; k < 18; ++k) {
            int q = t + k * 256;
            int c = q / 576, r2 = q - c * 576;
            int tap = r2 >> 6, ko = r2 & 63;
            wSrc[k] = ko * 4608 + c * 9 + tap;
        }
    }

    const float* fb = feat + (size_t)(cz * cin_blk) * NPIX;
    float acc0[20], acc1[20];
#pragma unroll
    for (int p = 0; p < 20; ++p) { acc0[p] = 0.f; acc1[p] = 0.f; }

    const int niter = cin_blk >> 3;
#pragma unroll 1
    for (int it = 0; it < niter; ++it) {
        __syncthreads();
#pragma unroll
        for (int k = 0; k < 11; ++k)
            if ((inValid >> k) & 1) in_l[t + k * 256] = fb[inSrc[k]];
        if (USEWT) {
#pragma unroll
            for (int k = 0; k < 18; ++k)
                w_l[t + k * 256] = wb[wOffA + k * 2048];
        } else {
#pragma unroll
            for (int k = 0; k < 18; ++k)
                w_l[t + k * 256] = wb[wSrc[k]];
        }
        __syncthreads();
#pragma unroll 1
        for (int c = 0; c < 8; ++c) {
            const float* ir0 = &in_l[(c * 4 + row) * 84 + x0];
            const float* wl  = &w_l[c * 576 + 2 * kp];
#pragma unroll
            for (int r = 0; r < 3; ++r) {
                const float* ir = ir0 + r * 84;
                float win[22];
#pragma unroll
                for (int w = 0; w < 22; ++w) win[w] = ir[w];
                float w00 = wl[(r * 3 + 0) * 64],     w01 = wl[(r * 3 + 1) * 64],     w02 = wl[(r * 3 + 2) * 64];
                float w10 = wl[(r * 3 + 0) * 64 + 1], w11 = wl[(r * 3 + 1) * 64 + 1], w12 = wl[(r * 3 + 2) * 64 + 1];
#pragma unroll
                for (int p = 0; p < 20; ++p) {
                    acc0[p] = fmaf(w00, win[p],     acc0[p]);
                    acc0[p] = fmaf(w01, win[p + 1], acc0[p]);
                    acc0[p] = fmaf(w02, win[p + 2], acc0[p]);
                    acc1[p] = fmaf(w10, win[p],     acc1[p]);
                    acc1[p] = fmaf(w11, win[p + 1], acc1[p]);
                    acc1[p] = fmaf(w12, win[p + 2], acc1[p]);
                }
            }
        }
        fb += 8 * NPIX;
        wb += USEWT ? 8 * 9 * 512 : 72;
    }

    const int k0 = kg * 64 + 2 * kp;
    const int y = yb * 2 + row;
    float* d0 = Xp + ((size_t)cz * 512 + k0) * NPIX + y * 76 + x0;
#pragma unroll
    for (int p = 0; p < 20; p += 2) {
        if (x0 + p + 1 < 76) {
            *reinterpret_cast<float2*>(d0 + p)        = make_float2(acc0[p], acc0[p + 1]);
            *reinterpret_cast<float2*>(d0 + NPIX + p) = make_float2(acc1[p], acc1[p + 1]);
        }
    }
}

// ---------------- combine: reduce split-K + bias + relu + transpose ----------------
__global__ __launch_bounds__(256) void rpn_combine(
    const float* __restrict__ Xp, const float* __restrict__ bias,
    float* __restrict__ Xt, int nz) {
    const int p0 = blockIdx.x * 256;
    const int c0 = blockIdx.y * 16;
    const int t  = threadIdx.x;
    __shared__ float s[16][257];
    const int p = p0 + t;
#pragma unroll 4
    for (int i = 0; i < 16; ++i) {
        float v = 0.f;
        if (p < NPIX) {
            size_t base = (size_t)(c0 + i) * NPIX + p;
            float a = bias[c0 + i];
            for (int z = 0; z < nz; ++z) a += Xp[(size_t)z * 512 * NPIX + base];
            v = fmaxf(a, 0.f);
        }
        s[i][t] = v;
    }
    __syncthreads();
    const int cs = (t & 3) * 4;
    const int pr = t >> 2;
#pragma unroll
    for (int q = 0; q < 4; ++q) {
        int p2 = p0 + pr + q * 64;
        if (p2 < NPIX) {
            int pi = pr + q * 64;
            float4 v = make_float4(s[cs][pi], s[cs + 1][pi], s[cs + 2][pi], s[cs + 3][pi]);
            *reinterpret_cast<float4*>(&Xt[(size_t)p2 * 512 + c0 + cs]) = v;
        }
    }
}

// ---------------- head: 1x1 convs + softmax + anchors + loc2bbox ----------------
__global__ __launch_bounds__(64) void rpn_head(
    const float* __restrict__ Xt,
    const float* __restrict__ sw, const float* __restrict__ sb,
    const float* __restrict__ lw, const float* __restrict__ lb,
    const int* __restrict__ ihp, const int* __restrict__ iwp,
    float* __restrict__ out, float* __restrict__ boxes,
    u32* __restrict__ keys, u32* __restrict__ hist) {
    const int p = blockIdx.x;
    const int t = threadIdx.x;
    __shared__ __align__(16) float xs[CIN];
    __shared__ float ov[64];
    const float4* xr = reinterpret_cast<const float4*>(Xt + (size_t)p * 512);
    reinterpret_cast<float4*>(xs)[t]      = xr[t];
    reinterpret_cast<float4*>(xs)[t + 64] = xr[t + 64];
    __syncthreads();
    if (t < 54) {
        const float* wr = (t < 18) ? (sw + t * CIN) : (lw + (t - 18) * CIN);
        float a = 0.f;
#pragma unroll 4
        for (int c = 0; c < CIN; c += 4) {
            float4 wv = *reinterpret_cast<const float4*>(wr + c);
            float4 xv = *reinterpret_cast<const float4*>(xs + c);
            a = fmaf(wv.x, xv.x, a); a = fmaf(wv.y, xv.y, a);
            a = fmaf(wv.z, xv.z, a); a = fmaf(wv.w, xv.w, a);
        }
        a += (t < 18) ? sb[t] : lb[t - 18];
        ov[t] = a;
    }
    __syncthreads();
    if (t < 9) {
        const int a = t;
        const float s0 = ov[2 * a], s1 = ov[2 * a + 1];
        const float dy = ov[18 + 4 * a], dx = ov[18 + 4 * a + 1];
        const float dh = ov[18 + 4 * a + 2], dw = ov[18 + 4 * a + 3];
        const int yy = p / WW2, xx = p % WW2;
        const int ai = p * 9 + a;
        *reinterpret_cast<float4*>(out + ai * 4) = make_float4(dy, dx, dh, dw);
        *reinterpret_cast<float2*>(out + 136800 + ai * 2) = make_float2(s0, s1);
        double r  = (a < 3) ? 0.5 : (a < 6) ? 1.0 : 2.0;
        int m3 = a % 3;
        double s2 = (m3 == 0) ? 8.0 : (m3 == 1) ? 16.0 : 32.0;
        double hd = (16.0 * s2) * sqrt(r);
        double wd = (16.0 * s2) * sqrt(1.0 / r);
        float ay1 = (float)(8.0 - hd * 0.5), ax1 = (float)(8.0 - wd * 0.5);
        float ay2 = (float)(8.0 + hd * 0.5), ax2 = (float)(8.0 + wd * 0.5);
        float fy = (float)(yy * 16), fx = (float)(xx * 16);
        float A0 = ay1 + fy, A1 = ax1 + fx, A2 = ay2 + fy, A3 = ax2 + fx;
        *reinterpret_cast<float4*>(out + 206400 + ai * 4) = make_float4(A0, A1, A2, A3);
        float ah = __fsub_rn(A2, A0), aw = __fsub_rn(A3, A1);
        float cy = __fadd_rn(A0, __fmul_rn(0.5f, ah));
        float cx = __fadd_rn(A1, __fmul_rn(0.5f, aw));
        float ncy = __fadd_rn(__fmul_rn(dy, ah), cy);
        float ncx = __fadd_rn(__fmul_rn(dx, aw), cx);
        float nh = __fmul_rn(expf(dh), ah);
        float nw = __fmul_rn(expf(dw), aw);
        float b0 = __fsub_rn(ncy, __fmul_rn(0.5f, nh));
        float b1 = __fsub_rn(ncx, __fmul_rn(0.5f, nw));
        float b2 = __fadd_rn(ncy, __fmul_rn(0.5f, nh));
        float b3 = __fadd_rn(ncx, __fmul_rn(0.5f, nw));
        const float ch = (float)(*ihp), cw = (float)(*iwp);
        b0 = fminf(fmaxf(b0, 0.f), ch); b2 = fminf(fmaxf(b2, 0.f), ch);
        b1 = fminf(fmaxf(b1, 0.f), cw); b3 = fminf(fmaxf(b3, 0.f), cw);
        float hs = __fsub_rn(b2, b0), wsz = __fsub_rn(b3, b1);
        float m = fmaxf(s0, s1);
        float e0 = expf(__fsub_rn(s0, m)), e1 = expf(__fsub_rn(s1, m));
        float fg = __fdiv_rn(e1, __fadd_rn(e0, e1));
        float score = (hs >= 16.f && wsz >= 16.f) ? fg : -__builtin_inff();
        *reinterpret_cast<float4*>(boxes + ai * 4) = make_float4(b0, b1, b2, b3);
        u32 kb = __float_as_uint(score);
        kb = (kb & 0x80000000u) ? ~kb : (kb | 0x80000000u);
        keys[ai] = kb;
        atomicAdd(&hist[kb >> 16], 1u);
    }
}

// ---------------- find 6000-th threshold bin ----------------
__global__ __launch_bounds__(256) void rpn_thresh(const u32* __restrict__ hist,
                                                  u32* __restrict__ info) {
    __shared__ u32 part[256];
    const int t = threadIdx.x;
    u32 s = 0;
    for (int b = 0; b < 256; ++b) s += hist[t * 256 + b];
    part[t] = s;
    __syncthreads();
    if (t == 0) {
        u32 cum = 0; int seg = 255;
        for (; seg >= 0; --seg) {
            if (cum + part[seg] >= NPRE) break;
            cum += part[seg];
        }
        u32 T = 0, n = cum;
        if (seg >= 0) {
            int b = seg * 256 + 255;
            for (; b >= seg * 256; --b) { n += hist[b]; if (n >= NPRE) break; }
            T = (u32)b;
        }
        info[0] = T; info[1] = n;
    }
}

// ---------------- select candidates (bin >= T) ----------------
__global__ void rpn_select(const u32* __restrict__ keys, u32* __restrict__ info,
                           u64* __restrict__ selk) {
    int idx = blockIdx.x * 256 + threadIdx.x;
    if (idx >= NANCH) return;
    u32 k = keys[idx];
    if ((k >> 16) >= info[0]) {
        u32 pos = atomicAdd(&info[2], 1u);
        if (pos < 8192) selk[pos] = ((u64)k << 32) | (u64)(0xFFFFFFFFu - (u32)idx);
    }
}

// ---------------- bitonic sort 8192 u64 desc; gather top-6000 boxes ----------------
__global__ __launch_bounds__(512) void rpn_sort(const u64* __restrict__ selk,
                                                const u32* __restrict__ info,
                                                const float* __restrict__ boxes,
                                                float* __restrict__ bk) {
    __shared__ u64 s[8192];
    const int t = threadIdx.x;
    int n = (int)info[2]; if (n > 8192) n = 8192;
    for (int i = t; i < 8192; i += 512) s[i] = (i < n) ? selk[i] : 0ull;
    __syncthreads();
    for (int k = 2; k <= 8192; k <<= 1) {
        for (int j = k >> 1; j > 0; j >>= 1) {
            for (int i = t; i < 8192; i += 512) {
                int ixj = i ^ j;
                if (ixj > i) {
                    u64 A = s[i], B = s[ixj];
                    bool desc = ((i & k) == 0);
                    if (desc ? (A < B) : (A > B)) { s[i] = B; s[ixj] = A; }
                }
            }
            __syncthreads();
        }
    }
    for (int r = t; r < NPRE; r += 512) {
        u32 oi = 0xFFFFFFFFu - (u32)(s[r] & 0xFFFFFFFFull);
        if (oi >= NANCH) oi = 0;
        reinterpret_cast<float4*>(bk)[r] = reinterpret_cast<const float4*>(boxes)[oi];
    }
}

// ---------------- IoU bitmask ----------------
__global__ __launch_bounds__(64) void rpn_iou(const float* __restrict__ bk,
                                              u64* __restrict__ mask) {
    const int t = threadIdx.x;
    const int bj = blockIdx.x, bi = blockIdx.y;
    __shared__ float4 jb[64];
    const int j0 = bj * 64;
    jb[t] = (j0 + t < NPRE) ? reinterpret_cast<const float4*>(bk)[j0 + t]
                            : make_float4(0.f, 0.f, 0.f, 0.f);
    __syncthreads();
    const int i = bi * 64 + t;
    if (i >= NPRE) return;
    float4 b = reinterpret_cast<const float4*>(bk)[i];
    float areai = __fmul_rn(__fsub_rn(b.z, b.x), __fsub_rn(b.w, b.y));
    u64 bits = 0ull;
    for (int jj = 0; jj < 64; ++jj) {
        int j = j0 + jj;
        if (j <= i || j >= NPRE) continue;
        float4 c = jb[jj];
        float ty = fmaxf(b.x, c.x), tx = fmaxf(b.y, c.y);
        float by = fminf(b.z, c.z), bx2 = fminf(b.w, c.w);
        float ih = fmaxf(__fsub_rn(by, ty), 0.f);
        float iw = fmaxf(__fsub_rn(bx2, tx), 0.f);
        float inter = __fmul_rn(ih, iw);
        float areaj = __fmul_rn(__fsub_rn(c.z, c.x), __fsub_rn(c.w, c.y));
        float denom = __fadd_rn(__fsub_rn(__fadd_rn(areai, areaj), inter), 1e-9f);
        float iou = __fdiv_rn(inter, denom);
        if (iou > 0.7f) bits |= (1ull << jj);
    }
    mask[(size_t)i * WPR + bj] = bits;
}

// ---------------- sequential greedy NMS (single wave, early-exit) ----------------
__global__ __launch_bounds__(64) void rpn_nms(const u64* __restrict__ mask,
                                              const float* __restrict__ bk,
                                              float* __restrict__ rois) {
    const int lane = threadIdx.x;
    u64 rem0 = 0ull, rem1 = 0ull, curW = 0ull;
    __shared__ unsigned short klist[304];
    int kcnt = 0;
    u64 pm0[16], pm1[16], pmg[16];
#pragma unroll
    for (int u = 0; u < 16; ++u) {
        pm0[u] = mask[(size_t)u * WPR + lane];
        pm1[u] = mask[(size_t)u * WPR + 64 + lane];
        pmg[u] = mask[(size_t)u * WPR + 0];
    }
    bool done = false;
    for (int base = 0; base < NPRE && !done; base += 16) {
        if ((base & 63) == 0) {
            int w = base >> 6;
            curW = (w < 64) ? __shfl(rem0, w) : __shfl(rem1, w - 64);
        }
#pragma unroll
        for (int u = 0; u < 16; ++u) {
            const int i = base + u;
            u64 m0 = pm0[u], m1 = pm1[u], mg = pmg[u];
            const int ni = i + 16;
            pm0[u] = mask[(size_t)ni * WPR + lane];
            pm1[u] = mask[(size_t)ni * WPR + 64 + lane];
            pmg[u] = mask[(size_t)ni * WPR + (ni >> 6)];
            if (((curW >> (i & 63)) & 1ull) == 0ull) {
                rem0 |= m0;
                if (lane < 30) rem1 |= m1;
                curW |= mg;
                if (lane == 0 && kcnt < 304) klist[kcnt] = (unsigned short)i;
                ++kcnt;
                if (kcnt >= NPOST) { done = true; break; }
            }
        }
    }
    __syncthreads();
    const int nk = kcnt < NPOST ? kcnt : NPOST;
    for (int r = lane; r < nk; r += 64) {
        int bi = klist[r];
        reinterpret_cast<float4*>(rois)[r] = reinterpret_cast<const float4*>(bk)[bi];
    }
    if (kcnt < NPOST) {
        int pos = kcnt;
        for (int i = 0; i < NPRE && pos < NPOST; ++i) {
            int w = i >> 6;
            u64 wv = (w < 64) ? __shfl(rem0, w) : __shfl(rem1, w - 64);
            if ((wv >> (i & 63)) & 1ull) {
                if (lane < 4) rois[pos * 4 + lane] = bk[i * 4 + lane];
                ++pos;
            }
        }
    }
}

extern "C" void kernel_launch(void* const* d_in, const int* in_sizes, int n_in,
                              void* d_out, int out_size, void* d_ws, size_t ws_size,
                              hipStream_t stream) {
    (void)in_sizes; (void)n_in; (void)out_size;
    const float* feat = (const float*)d_in[0];
    const float* w1   = (const float*)d_in[1];
    const float* b1   = (const float*)d_in[2];
    const float* sw   = (const float*)d_in[3];
    const float* sb   = (const float*)d_in[4];
    const float* lw   = (const float*)d_in[5];
    const float* lb   = (const float*)d_in[6];
    const int*   ih   = (const int*)d_in[7];
    const int*   iw   = (const int*)d_in[8];
    float* out = (float*)d_out;

    // --- dynamic workspace layout: XP(nz), [WT], XT, BOXES, KEYS, HIST, INFO, SELK, BK, MASK
    const size_t WT_B    = 9437184;   // 512*512*9*4
    const size_t XT_B    = 7782400;
    const size_t REST_B  = 547200 + 136800 + 262144 + 64 + 65536 + 96000 + 4528128;
    const size_t SLICE_B = (size_t)512 * NPIX * 4;   // one split-K partial: 7.78MB
    int nz; bool usewt;
    if      (ws_size >= 8 * SLICE_B + WT_B + XT_B + REST_B) { nz = 8; usewt = true; }
    else if (ws_size >= 4 * SLICE_B + WT_B + XT_B + REST_B) { nz = 4; usewt = true; }
    else if (ws_size >= 2 * SLICE_B + WT_B + XT_B + REST_B) { nz = 2; usewt = true; }
    else                                                    { nz = 2; usewt = false; }

    char* p = (char*)d_ws;
    float* Xp = (float*)p;           p += (size_t)nz * SLICE_B;
    float* wt = nullptr;
    if (usewt) { wt = (float*)p;     p += WT_B; }
    float* Xt     = (float*)p;       p += XT_B;
    float* boxes  = (float*)p;       p += 547200;
    u32*   keys   = (u32*)p;         p += 136800;
    u32*   hist   = (u32*)p;         p += 262144;
    u32*   info   = (u32*)p;         p += 64;
    u64*   selk   = (u64*)p;         p += 65536;
    float* bk     = (float*)p;       p += 96000;
    u64*   mask   = (u64*)p;

    const int cin_blk = 512 / nz;

    rpn_init<<<258, 256, 0, stream>>>(hist, info);
    if (usewt) {
        rpn_wtrans<<<9216, 256, 0, stream>>>(w1, wt);
        rpn_conv1<true><<<dim3(25, 8, nz), 256, 0, stream>>>(feat, wt, Xp, cin_blk);
    } else {
        rpn_conv1<false><<<dim3(25, 8, nz), 256, 0, stream>>>(feat, w1, Xp, cin_blk);
    }
    rpn_combine<<<dim3(15, 32), 256, 0, stream>>>(Xp, b1, Xt, nz);
    rpn_head<<<NPIX, 64, 0, stream>>>(Xt, sw, sb, lw, lb, ih, iw, out, boxes, keys, hist);
    rpn_thresh<<<1, 256, 0, stream>>>(hist, info);
    rpn_select<<<(NANCH + 255) / 256, 256, 0, stream>>>(keys, info, selk);
    rpn_sort<<<1, 512, 0, stream>>>(selk, info, boxes, bk);
    rpn_iou<<<dim3(WPR, WPR), 64, 0, stream>>>(bk, mask);
    rpn_nms<<<1, 64, 0, stream>>>(mask, bk, out + 205200);
}

// Round 4
// 659.587 us; speedup vs baseline: 2.4096x; 1.2752x over previous
//
#include <hip/hip_runtime.h>

// ---------------- problem constants ----------------
#define HH 50
#define WW2 76
#define NPIX 3800
#define CIN 512
#define NANCH 34200     // 3800*9
#define NPRE 6000
#define NPOST 300
#define WPR 94          // ceil(6000/64) words per mask row

typedef unsigned long long u64;
typedef unsigned int u32;

// ---------------- weight transpose + zero hist/info ----------------
// wt[(ci*9+tap)*512 + ko]; grid 9216x256 covers 512*512*9 = 2359296 exactly
__global__ __launch_bounds__(256) void rpn_wtrans(const float* __restrict__ wgt,
                                                  float* __restrict__ wt,
                                                  u32* __restrict__ hist,
                                                  u32* __restrict__ info) {
    int id = blockIdx.x * 256 + threadIdx.x;
    if (id < 65536) hist[id] = 0u;
    else if (id < 65552) info[id - 65536] = 0u;
    int ko = id & 511;
    int tmp = id >> 9;            // ci*9 + tap
    int tap = tmp % 9, ci = tmp / 9;
    wt[id] = wgt[(size_t)ko * 4608 + ci * 9 + tap];
}

// ---------------- conv1: 3x3, 512->512, pad 1, split-K partials ----------------
// (unchanged from round 3: 291 us, VALUBusy 62%, 0 bank conflicts)
template <bool USEWT>
__global__ __launch_bounds__(256, 4) void rpn_conv1(
    const float* __restrict__ feat, const float* __restrict__ wsrc,
    float* __restrict__ Xp, int cin_blk) {
    const int yb = blockIdx.x;
    const int kg = blockIdx.y;
    const int cz = blockIdx.z;
    const int t  = threadIdx.x;
    const int kp = t & 31;
    const int ty = t >> 5;
    const int row  = ty >> 2;
    const int xseg = ty & 3;
    const int x0 = xseg * 20;
    __shared__ float in_l[2816];       // 8c*4r*84 = 2688 used
    __shared__ float w_l[4608];        // 18 chunks of 256, exact

    const int y0 = yb * 2 - 1;
    int inSrc[11]; u32 inValid = 0, inPad = 0;
#pragma unroll
    for (int k = 0; k < 11; ++k) {
        int q = t + k * 256;
        int c = q / 336, rem = q - c * 336;
        int r = rem / 84, xx = rem - r * 84;
        int gy = y0 + r, gx = xx - 1;
        bool inb = q < 2688;
        bool ok = inb && ((unsigned)gy < 50u) && ((unsigned)gx < 76u);
        inSrc[k] = c * NPIX + gy * 76 + gx;
        if (ok) inValid |= (1u << k);
        else if (inb) inPad |= (1u << k);
    }
#pragma unroll
    for (int k = 0; k < 11; ++k)
        if ((inPad >> k) & 1) in_l[t + k * 256] = 0.f;

    const float* wb;
    int wOffA = 0;
    int wSrc[18];
    if (USEWT) {
        wb = wsrc + (size_t)(cz * cin_blk) * 9 * 512 + kg * 64;
        wOffA = 8 * t - 7 * (t & 63);
    } else {
        wb = wsrc + (size_t)(kg * 64) * 4608 + (size_t)(cz * cin_blk) * 9;
#pragma unroll
        for (int k = 0; k < 18; ++k) {
            int q = t + k * 256;
            int c = q / 576, r2 = q - c * 576;
            int tap = r2 >> 6, ko = r2 & 63;
            wSrc[k] = ko * 4608 + c * 9 + tap;
        }
    }

    const float* fb = feat + (size_t)(cz * cin_blk) * NPIX;
    float acc0[20], acc1[20];
#pragma unroll
    for (int p = 0; p < 20; ++p) { acc0[p] = 0.f; acc1[p] = 0.f; }

    const int niter = cin_blk >> 3;
#pragma unroll 1
    for (int it = 0; it < niter; ++it) {
        __syncthreads();
#pragma unroll
        for (int k = 0; k < 11; ++k)
            if ((inValid >> k) & 1) in_l[t + k * 256] = fb[inSrc[k]];
        if (USEWT) {
#pragma unroll
            for (int k = 0; k < 18; ++k)
                w_l[t + k * 256] = wb[wOffA + k * 2048];
        } else {
#pragma unroll
            for (int k = 0; k < 18; ++k)
                w_l[t + k * 256] = wb[wSrc[k]];
        }
        __syncthreads();
#pragma unroll 1
        for (int c = 0; c < 8; ++c) {
            const float* ir0 = &in_l[(c * 4 + row) * 84 + x0];
            const float* wl  = &w_l[c * 576 + 2 * kp];
#pragma unroll
            for (int r = 0; r < 3; ++r) {
                const float* ir = ir0 + r * 84;
                float win[22];
#pragma unroll
                for (int w = 0; w < 22; ++w) win[w] = ir[w];
                float w00 = wl[(r * 3 + 0) * 64],     w01 = wl[(r * 3 + 1) * 64],     w02 = wl[(r * 3 + 2) * 64];
                float w10 = wl[(r * 3 + 0) * 64 + 1], w11 = wl[(r * 3 + 1) * 64 + 1], w12 = wl[(r * 3 + 2) * 64 + 1];
#pragma unroll
                for (int p = 0; p < 20; ++p) {
                    acc0[p] = fmaf(w00, win[p],     acc0[p]);
                    acc0[p] = fmaf(w01, win[p + 1], acc0[p]);
                    acc0[p] = fmaf(w02, win[p + 2], acc0[p]);
                    acc1[p] = fmaf(w10, win[p],     acc1[p]);
                    acc1[p] = fmaf(w11, win[p + 1], acc1[p]);
                    acc1[p] = fmaf(w12, win[p + 2], acc1[p]);
                }
            }
        }
        fb += 8 * NPIX;
        wb += USEWT ? 8 * 9 * 512 : 72;
    }

    const int k0 = kg * 64 + 2 * kp;
    const int y = yb * 2 + row;
    float* d0 = Xp + ((size_t)cz * 512 + k0) * NPIX + y * 76 + x0;
#pragma unroll
    for (int p = 0; p < 20; p += 2) {
        if (x0 + p + 1 < 76) {
            *reinterpret_cast<float2*>(d0 + p)        = make_float2(acc0[p], acc0[p + 1]);
            *reinterpret_cast<float2*>(d0 + NPIX + p) = make_float2(acc1[p], acc1[p + 1]);
        }
    }
}

// ---------------- combine: reduce split-K + bias + relu + transpose ----------------
__global__ __launch_bounds__(256) void rpn_combine(
    const float* __restrict__ Xp, const float* __restrict__ bias,
    float* __restrict__ Xt, int nz) {
    const int p0 = blockIdx.x * 256;
    const int c0 = blockIdx.y * 16;
    const int t  = threadIdx.x;
    __shared__ float s[16][257];
    const int p = p0 + t;
#pragma unroll 4
    for (int i = 0; i < 16; ++i) {
        float v = 0.f;
        if (p < NPIX) {
            size_t base = (size_t)(c0 + i) * NPIX + p;
            float a = bias[c0 + i];
            for (int z = 0; z < nz; ++z) a += Xp[(size_t)z * 512 * NPIX + base];
            v = fmaxf(a, 0.f);
        }
        s[i][t] = v;
    }
    __syncthreads();
    const int cs = (t & 3) * 4;
    const int pr = t >> 2;
#pragma unroll
    for (int q = 0; q < 4; ++q) {
        int p2 = p0 + pr + q * 64;
        if (p2 < NPIX) {
            int pi = pr + q * 64;
            float4 v = make_float4(s[cs][pi], s[cs + 1][pi], s[cs + 2][pi], s[cs + 3][pi]);
            *reinterpret_cast<float4*>(&Xt[(size_t)p2 * 512 + c0 + cs]) = v;
        }
    }
}

// ---------------- head: 1x1 convs + softmax + anchors + loc2bbox ----------------
__global__ __launch_bounds__(64) void rpn_head(
    const float* __restrict__ Xt,
    const float* __restrict__ sw, const float* __restrict__ sb,
    const float* __restrict__ lw, const float* __restrict__ lb,
    const int* __restrict__ ihp, const int* __restrict__ iwp,
    float* __restrict__ out, float* __restrict__ boxes,
    u32* __restrict__ keys, u32* __restrict__ hist) {
    const int p = blockIdx.x;
    const int t = threadIdx.x;
    __shared__ __align__(16) float xs[CIN];
    __shared__ float ov[64];
    const float4* xr = reinterpret_cast<const float4*>(Xt + (size_t)p * 512);
    reinterpret_cast<float4*>(xs)[t]      = xr[t];
    reinterpret_cast<float4*>(xs)[t + 64] = xr[t + 64];
    __syncthreads();
    if (t < 54) {
        const float* wr = (t < 18) ? (sw + t * CIN) : (lw + (t - 18) * CIN);
        float a = 0.f;
#pragma unroll 4
        for (int c = 0; c < CIN; c += 4) {
            float4 wv = *reinterpret_cast<const float4*>(wr + c);
            float4 xv = *reinterpret_cast<const float4*>(xs + c);
            a = fmaf(wv.x, xv.x, a); a = fmaf(wv.y, xv.y, a);
            a = fmaf(wv.z, xv.z, a); a = fmaf(wv.w, xv.w, a);
        }
        a += (t < 18) ? sb[t] : lb[t - 18];
        ov[t] = a;
    }
    __syncthreads();
    if (t < 9) {
        const int a = t;
        const float s0 = ov[2 * a], s1 = ov[2 * a + 1];
        const float dy = ov[18 + 4 * a], dx = ov[18 + 4 * a + 1];
        const float dh = ov[18 + 4 * a + 2], dw = ov[18 + 4 * a + 3];
        const int yy = p / WW2, xx = p % WW2;
        const int ai = p * 9 + a;
        *reinterpret_cast<float4*>(out + ai * 4) = make_float4(dy, dx, dh, dw);
        *reinterpret_cast<float2*>(out + 136800 + ai * 2) = make_float2(s0, s1);
        double r  = (a < 3) ? 0.5 : (a < 6) ? 1.0 : 2.0;
        int m3 = a % 3;
        double s2 = (m3 == 0) ? 8.0 : (m3 == 1) ? 16.0 : 32.0;
        double hd = (16.0 * s2) * sqrt(r);
        double wd = (16.0 * s2) * sqrt(1.0 / r);
        float ay1 = (float)(8.0 - hd * 0.5), ax1 = (float)(8.0 - wd * 0.5);
        float ay2 = (float)(8.0 + hd * 0.5), ax2 = (float)(8.0 + wd * 0.5);
        float fy = (float)(yy * 16), fx = (float)(xx * 16);
        float A0 = ay1 + fy, A1 = ax1 + fx, A2 = ay2 + fy, A3 = ax2 + fx;
        *reinterpret_cast<float4*>(out + 206400 + ai * 4) = make_float4(A0, A1, A2, A3);
        float ah = __fsub_rn(A2, A0), aw = __fsub_rn(A3, A1);
        float cy = __fadd_rn(A0, __fmul_rn(0.5f, ah));
        float cx = __fadd_rn(A1, __fmul_rn(0.5f, aw));
        float ncy = __fadd_rn(__fmul_rn(dy, ah), cy);
        float ncx = __fadd_rn(__fmul_rn(dx, aw), cx);
        float nh = __fmul_rn(expf(dh), ah);
        float nw = __fmul_rn(expf(dw), aw);
        float b0 = __fsub_rn(ncy, __fmul_rn(0.5f, nh));
        float b1 = __fsub_rn(ncx, __fmul_rn(0.5f, nw));
        float b2 = __fadd_rn(ncy, __fmul_rn(0.5f, nh));
        float b3 = __fadd_rn(ncx, __fmul_rn(0.5f, nw));
        const float ch = (float)(*ihp), cw = (float)(*iwp);
        b0 = fminf(fmaxf(b0, 0.f), ch); b2 = fminf(fmaxf(b2, 0.f), ch);
        b1 = fminf(fmaxf(b1, 0.f), cw); b3 = fminf(fmaxf(b3, 0.f), cw);
        float hs = __fsub_rn(b2, b0), wsz = __fsub_rn(b3, b1);
        float m = fmaxf(s0, s1);
        float e0 = expf(__fsub_rn(s0, m)), e1 = expf(__fsub_rn(s1, m));
        float fg = __fdiv_rn(e1, __fadd_rn(e0, e1));
        float score = (hs >= 16.f && wsz >= 16.f) ? fg : -__builtin_inff();
        *reinterpret_cast<float4*>(boxes + ai * 4) = make_float4(b0, b1, b2, b3);
        u32 kb = __float_as_uint(score);
        kb = (kb & 0x80000000u) ? ~kb : (kb | 0x80000000u);
        keys[ai] = kb;
        atomicAdd(&hist[kb >> 16], 1u);
    }
}

// ---------------- threshold bin: fully parallel suffix scans ----------------
__global__ __launch_bounds__(256) void rpn_thresh(const u32* __restrict__ hist,
                                                  u32* __restrict__ info) {
    __shared__ u32 part[256], h2[256];
    __shared__ int segs;
    const int t = threadIdx.x;
    u32 s = 0;
    const u32* hp = hist + t * 256;
    for (int b = 0; b < 256; ++b) s += hp[b];
    part[t] = s;
    __syncthreads();
    // suffix-sum part: part[t] = sum part[t..255]
    for (int off = 1; off < 256; off <<= 1) {
        u32 v = part[t];
        u32 add = (t + off < 256) ? part[t + off] : 0u;
        __syncthreads();
        part[t] = v + add;
        __syncthreads();
    }
    u32 suf  = part[t];
    u32 sufn = (t < 255) ? part[t + 1] : 0u;
    if (suf >= NPRE && sufn < NPRE) segs = t;
    __syncthreads();
    const int seg = segs;
    const u32 above = (seg < 255) ? part[seg + 1] : 0u;
    h2[t] = hist[seg * 256 + t];
    __syncthreads();
    for (int off = 1; off < 256; off <<= 1) {
        u32 v = h2[t];
        u32 add = (t + off < 256) ? h2[t + off] : 0u;
        __syncthreads();
        h2[t] = v + add;
        __syncthreads();
    }
    u32 tot  = above + h2[t];
    u32 totn = above + ((t < 255) ? h2[t + 1] : 0u);
    if (tot >= NPRE && totn < NPRE) info[0] = (u32)(seg * 256 + t);
}

// ---------------- select candidates (bin >= T) ----------------
__global__ void rpn_select(const u32* __restrict__ keys, u32* __restrict__ info,
                           u64* __restrict__ selk) {
    int idx = blockIdx.x * 256 + threadIdx.x;
    if (idx >= NANCH) return;
    u32 k = keys[idx];
    if ((k >> 16) >= info[0]) {
        u32 pos = atomicAdd(&info[2], 1u);
        if (pos < 8192) selk[pos] = ((u64)k << 32) | (u64)(0xFFFFFFFFu - (u32)idx);
    }
}

// ---------------- hierarchical bitonic sort: 8192 u64 desc, in-place in selk ----
// pair mapping: p1 = ((i & ~(j-1)) << 1) | (i & (j-1)), p2 = p1 | j
// canonical dir: pair descending iff ((p1 & k) == 0)  (full network -> desc)

// local full sort of 2048-seg to direction D = (seg even ? desc : asc)
__global__ __launch_bounds__(1024) void rpn_sort_local(u64* __restrict__ selk,
                                                       const u32* __restrict__ info) {
    __shared__ u64 s[2048];
    const int t = threadIdx.x;
    const int seg = blockIdx.x;
    const int base = seg * 2048;
    int n = (int)info[2]; if (n > 8192) n = 8192;
    for (int i = t; i < 2048; i += 1024) s[i] = (base + i < n) ? selk[base + i] : 0ull;
    __syncthreads();
    const bool D = ((seg & 1) == 0);
    for (int k = 2; k <= 2048; k <<= 1) {
        for (int j = k >> 1; j > 0; j >>= 1) {
            int p1 = ((t & ~(j - 1)) << 1) | (t & (j - 1));
            int p2 = p1 | j;
            bool desc = (((p1 & k) == 0) == D);
            u64 A = s[p1], B = s[p2];
            if (desc ? (A < B) : (A > B)) { s[p1] = B; s[p2] = A; }
            __syncthreads();
        }
    }
    for (int i = t; i < 2048; i += 1024) selk[base + i] = s[i];
}

// one global exchange pass (k, j) over 4096 pairs; grid 8 x 512
__global__ __launch_bounds__(512) void rpn_sort_gpass(u64* __restrict__ selk,
                                                      int k, int j) {
    int i = blockIdx.x * 512 + threadIdx.x;
    int p1 = ((i & ~(j - 1)) << 1) | (i & (j - 1));
    int p2 = p1 | j;
    bool desc = ((p1 & k) == 0);
    u64 A = selk[p1], B = selk[p2];
    if (desc ? (A < B) : (A > B)) { selk[p1] = B; selk[p2] = A; }
}

// local merge (j = 1024..1) for stage k; k > 2048 so dir uniform per segment.
// FINAL: fuse the top-6000 box gather.
template <bool FINAL>
__global__ __launch_bounds__(1024) void rpn_sort_lmerge(u64* __restrict__ selk, int k,
                                                        const float* __restrict__ boxes,
                                                        float* __restrict__ bk) {
    __shared__ u64 s[2048];
    const int t = threadIdx.x;
    const int seg = blockIdx.x;
    const int base = seg * 2048;
    for (int i = t; i < 2048; i += 1024) s[i] = selk[base + i];
    __syncthreads();
    const bool desc = ((base & k) == 0);
    for (int j = 1024; j > 0; j >>= 1) {
        int p1 = ((t & ~(j - 1)) << 1) | (t & (j - 1));
        int p2 = p1 | j;
        u64 A = s[p1], B = s[p2];
        if (desc ? (A < B) : (A > B)) { s[p1] = B; s[p2] = A; }
        __syncthreads();
    }
    if (FINAL) {
        for (int i = t; i < 2048; i += 1024) {
            int r = base + i;
            if (r < NPRE) {
                u32 oi = 0xFFFFFFFFu - (u32)(s[i] & 0xFFFFFFFFull);
                if (oi >= NANCH) oi = 0;
                reinterpret_cast<float4*>(bk)[r] = reinterpret_cast<const float4*>(boxes)[oi];
            }
        }
    } else {
        for (int i = t; i < 2048; i += 1024) selk[base + i] = s[i];
    }
}

// ---------------- IoU bitmask (lower-triangle blocks short-circuit) ----------------
__global__ __launch_bounds__(64) void rpn_iou(const float* __restrict__ bk,
                                              u64* __restrict__ mask) {
    const int t = threadIdx.x;
    const int bj = blockIdx.x, bi = blockIdx.y;
    const int j0 = bj * 64;
    const int i = bi * 64 + t;
    if (j0 + 63 <= bi * 64) {           // block-uniform: all pairs have j <= i
        if (i < NPRE) mask[(size_t)i * WPR + bj] = 0ull;
        return;
    }
    __shared__ float4 jb[64];
    jb[t] = (j0 + t < NPRE) ? reinterpret_cast<const float4*>(bk)[j0 + t]
                            : make_float4(0.f, 0.f, 0.f, 0.f);
    __syncthreads();
    if (i >= NPRE) return;
    float4 b = reinterpret_cast<const float4*>(bk)[i];
    float areai = __fmul_rn(__fsub_rn(b.z, b.x), __fsub_rn(b.w, b.y));
    u64 bits = 0ull;
    for (int jj = 0; jj < 64; ++jj) {
        int j = j0 + jj;
        if (j <= i || j >= NPRE) continue;
        float4 c = jb[jj];
        float ty = fmaxf(b.x, c.x), tx = fmaxf(b.y, c.y);
        float by = fminf(b.z, c.z), bx2 = fminf(b.w, c.w);
        float ih = fmaxf(__fsub_rn(by, ty), 0.f);
        float iw = fmaxf(__fsub_rn(bx2, tx), 0.f);
        float inter = __fmul_rn(ih, iw);
        float areaj = __fmul_rn(__fsub_rn(c.z, c.x), __fsub_rn(c.w, c.y));
        float denom = __fadd_rn(__fsub_rn(__fadd_rn(areai, areaj), inter), 1e-9f);
        float iou = __fdiv_rn(inter, denom);
        if (iou > 0.7f) bits |= (1ull << jj);
    }
    mask[(size_t)i * WPR + bj] = bits;
}

// ---------------- sequential greedy NMS (single wave, early-exit) ----------------
__global__ __launch_bounds__(64) void rpn_nms(const u64* __restrict__ mask,
                                              const float* __restrict__ bk,
                                              float* __restrict__ rois) {
    const int lane = threadIdx.x;
    u64 rem0 = 0ull, rem1 = 0ull, curW = 0ull;
    __shared__ unsigned short klist[304];
    int kcnt = 0;
    u64 pm0[16], pm1[16], pmg[16];
#pragma unroll
    for (int u = 0; u < 16; ++u) {
        pm0[u] = mask[(size_t)u * WPR + lane];
        pm1[u] = (lane < 30) ? mask[(size_t)u * WPR + 64 + lane] : 0ull;
        pmg[u] = mask[(size_t)u * WPR + 0];
    }
    bool done = false;
    for (int base = 0; base < NPRE && !done; base += 16) {
        if ((base & 63) == 0) {
            int w = base >> 6;
            curW = (w < 64) ? __shfl(rem0, w) : __shfl(rem1, w - 64);
        }
#pragma unroll
        for (int u = 0; u < 16; ++u) {
            const int i = base + u;
            u64 m0 = pm0[u], m1 = pm1[u], mg = pmg[u];
            const int ni = i + 16;
            pm0[u] = mask[(size_t)ni * WPR + lane];
            pm1[u] = (lane < 30) ? mask[(size_t)ni * WPR + 64 + lane] : 0ull;
            pmg[u] = mask[(size_t)ni * WPR + (ni >> 6)];
            if (((curW >> (i & 63)) & 1ull) == 0ull) {
                rem0 |= m0;
                rem1 |= m1;
                curW |= mg;
                if (lane == 0 && kcnt < 304) klist[kcnt] = (unsigned short)i;
                ++kcnt;
                if (kcnt >= NPOST) { done = true; break; }
            }
        }
    }
    __syncthreads();
    const int nk = kcnt < NPOST ? kcnt : NPOST;
    for (int r = lane; r < nk; r += 64) {
        int bi = klist[r];
        reinterpret_cast<float4*>(rois)[r] = reinterpret_cast<const float4*>(bk)[bi];
    }
    if (kcnt < NPOST) {
        int pos = kcnt;
        for (int i = 0; i < NPRE && pos < NPOST; ++i) {
            int w = i >> 6;
            u64 wv = (w < 64) ? __shfl(rem0, w) : __shfl(rem1, w - 64);
            if ((wv >> (i & 63)) & 1ull) {
                if (lane < 4) rois[pos * 4 + lane] = bk[i * 4 + lane];
                ++pos;
            }
        }
    }
}

extern "C" void kernel_launch(void* const* d_in, const int* in_sizes, int n_in,
                              void* d_out, int out_size, void* d_ws, size_t ws_size,
                              hipStream_t stream) {
    (void)in_sizes; (void)n_in; (void)out_size;
    const float* feat = (const float*)d_in[0];
    const float* w1   = (const float*)d_in[1];
    const float* b1   = (const float*)d_in[2];
    const float* sw   = (const float*)d_in[3];
    const float* sb   = (const float*)d_in[4];
    const float* lw   = (const float*)d_in[5];
    const float* lb   = (const float*)d_in[6];
    const int*   ih   = (const int*)d_in[7];
    const int*   iw   = (const int*)d_in[8];
    float* out = (float*)d_out;

    const size_t WT_B    = 9437184;   // 512*512*9*4
    const size_t XT_B    = 7782400;
    const size_t REST_B  = 547200 + 136800 + 262144 + 64 + 65536 + 96000 + 4528128;
    const size_t SLICE_B = (size_t)512 * NPIX * 4;
    int nz; bool usewt;
    if      (ws_size >= 8 * SLICE_B + WT_B + XT_B + REST_B) { nz = 8; usewt = true; }
    else if (ws_size >= 4 * SLICE_B + WT_B + XT_B + REST_B) { nz = 4; usewt = true; }
    else if (ws_size >= 2 * SLICE_B + WT_B + XT_B + REST_B) { nz = 2; usewt = true; }
    else                                                    { nz = 2; usewt = false; }

    char* p = (char*)d_ws;
    float* Xp = (float*)p;           p += (size_t)nz * SLICE_B;
    float* wt = nullptr;
    if (usewt) { wt = (float*)p;     p += WT_B; }
    float* Xt     = (float*)p;       p += XT_B;
    float* boxes  = (float*)p;       p += 547200;
    u32*   keys   = (u32*)p;         p += 136800;
    u32*   hist   = (u32*)p;         p += 262144;
    u32*   info   = (u32*)p;         p += 64;
    u64*   selk   = (u64*)p;         p += 65536;
    float* bk     = (float*)p;       p += 96000;
    u64*   mask   = (u64*)p;

    const int cin_blk = 512 / nz;

    if (usewt) {
        rpn_wtrans<<<9216, 256, 0, stream>>>(w1, wt, hist, info);
        rpn_conv1<true><<<dim3(25, 8, nz), 256, 0, stream>>>(feat, wt, Xp, cin_blk);
    } else {
        rpn_wtrans<<<9216, 256, 0, stream>>>(w1, (float*)Xt, hist, info);  // hist/info zero only; wt dump into Xt (overwritten later)
        rpn_conv1<false><<<dim3(25, 8, nz), 256, 0, stream>>>(feat, w1, Xp, cin_blk);
    }
    rpn_combine<<<dim3(15, 32), 256, 0, stream>>>(Xp, b1, Xt, nz);
    rpn_head<<<NPIX, 64, 0, stream>>>(Xt, sw, sb, lw, lb, ih, iw, out, boxes, keys, hist);
    rpn_thresh<<<1, 256, 0, stream>>>(hist, info);
    rpn_select<<<(NANCH + 255) / 256, 256, 0, stream>>>(keys, info, selk);
    rpn_sort_local<<<4, 1024, 0, stream>>>(selk, info);
    rpn_sort_gpass<<<8, 512, 0, stream>>>(selk, 4096, 2048);
    rpn_sort_lmerge<false><<<4, 1024, 0, stream>>>(selk, 4096, nullptr, nullptr);
    rpn_sort_gpass<<<8, 512, 0, stream>>>(selk, 8192, 4096);
    rpn_sort_gpass<<<8, 512, 0, stream>>>(selk, 8192, 2048);
    rpn_sort_lmerge<true><<<4, 1024, 0, stream>>>(selk, 8192, boxes, bk);
    rpn_iou<<<dim3(WPR, WPR), 64, 0, stream>>>(bk, mask);
    rpn_nms<<<1, 64, 0, stream>>>(mask, bk, out + 205200);
}